// Round 1
// baseline (1375.715 us; speedup 1.0000x reference)
//
#include <hip/hip_runtime.h>
#include <hip/hip_bf16.h>

typedef unsigned short u16;
typedef __attribute__((ext_vector_type(8))) short bf16x8;
typedef __attribute__((ext_vector_type(4))) float f32x4;

#define MFMA16(a, b, c) __builtin_amdgcn_mfma_f32_16x16x32_bf16((a), (b), (c), 0, 0, 0)

// global -> LDS direct copy, 16B per lane. Dest must be wave-uniform base; the
// hardware writes base + lane*16.
#define GLD16(src, dst)                                                        \
    __builtin_amdgcn_global_load_lds(                                          \
        (const __attribute__((address_space(1))) void*)(src),                  \
        (__attribute__((address_space(3))) void*)(dst), 16, 0, 0)

__device__ __forceinline__ float bf2f(u16 u) {
    union { unsigned int i; float f; } v;
    v.i = ((unsigned int)u) << 16;
    return v.f;
}
__device__ __forceinline__ u16 f2bf(float f) {
    unsigned int x = __float_as_uint(f);
    x += 0x7FFFu + ((x >> 16) & 1u);   // RNE
    return (u16)(x >> 16);
}

// ---------------------------------------------------------------------------
// rope table: tab[s][p] = (cos, sin)(pos * 10000^(-p/16)), pos = 8976 + s
// ---------------------------------------------------------------------------
__global__ void rope_table_kernel(float2* __restrict__ tab) {
    int i = blockIdx.x * 256 + threadIdx.x;
    if (i >= 1024 * 16) return;
    int s = i >> 4, p = i & 15;
    double ang = (double)(8976 + s) * pow(10000.0, -(double)p / 16.0);
    tab[i] = make_float2((float)cos(ang), (float)sin(ang));
}

// ---------------------------------------------------------------------------
// x fp32 [16M] -> bf16 (RNE), vectorized 8/thread.
// ---------------------------------------------------------------------------
__global__ __launch_bounds__(256) void xcast_kernel(const float* __restrict__ X,
                                                    u16* __restrict__ Xb, int n) {
    int i = (blockIdx.x * 256 + threadIdx.x) * 8;
    if (i >= n) return;
    float4 f0 = *(const float4*)(X + i);
    float4 f1 = *(const float4*)(X + i + 4);
    union { u16 u[8]; uint4 v; } o;
    o.u[0] = f2bf(f0.x); o.u[1] = f2bf(f0.y); o.u[2] = f2bf(f0.z); o.u[3] = f2bf(f0.w);
    o.u[4] = f2bf(f1.x); o.u[5] = f2bf(f1.y); o.u[6] = f2bf(f1.z); o.u[7] = f2bf(f1.w);
    *(uint4*)(Xb + i) = o.v;
}

// ---------------------------------------------------------------------------
// W [K,N] fp32 -> WT [N,K] bf16 (RNE). 64x64 tiles via LDS.
// ---------------------------------------------------------------------------
__global__ __launch_bounds__(256) void wt_kernel(const float* __restrict__ W,
                                                 u16* __restrict__ WT, int K, int N) {
    __shared__ u16 t[64][72];   // +8 pad breaks transpose bank conflicts
    const int kt = blockIdx.y * 64, nt = blockIdx.x * 64;
    const int tid = threadIdx.x;
#pragma unroll
    for (int i = 0; i < 4; i++) {
        int cid = tid + i * 256;           // 1024 float4 chunks
        int k = cid >> 4, c = cid & 15;
        float4 f = *(const float4*)(W + (size_t)(kt + k) * N + nt + c * 4);
        t[c * 4 + 0][k] = f2bf(f.x);
        t[c * 4 + 1][k] = f2bf(f.y);
        t[c * 4 + 2][k] = f2bf(f.z);
        t[c * 4 + 3][k] = f2bf(f.w);
    }
    __syncthreads();
#pragma unroll
    for (int i = 0; i < 2; i++) {
        int cid = tid + i * 256;           // 512 chunks of 8 u16
        int n = cid >> 3, c = cid & 7;
        union { u16 u[8]; uint4 v; } o;
#pragma unroll
        for (int j = 0; j < 8; j++) o.u[j] = t[n][c * 8 + j];
        *(uint4*)(WT + (size_t)(nt + n) * K + kt + c * 8) = o.v;
    }
}

// ---------------------------------------------------------------------------
// In-place partial rotary on first 32 channels of q and k (bf16 ws buffers).
// ---------------------------------------------------------------------------
__global__ void rope_apply_kernel(u16* __restrict__ q, u16* __restrict__ k,
                                  const float2* __restrict__ tab) {
    int i = blockIdx.x * 256 + threadIdx.x;   // (b*1024 + s)*32 + h
    if (i >= 4 * 1024 * 32) return;
    int s = (i >> 5) & 1023;
    const float2* tp = tab + s * 16;
    u16* ptrs[2] = { q + (size_t)i * 128, k + (size_t)i * 128 };
#pragma unroll
    for (int t = 0; t < 2; t++) {
        u16* p = ptrs[t];
        u16 buf[32], outb[32];
        *(uint4*)(buf)      = *(const uint4*)(p);
        *(uint4*)(buf + 8)  = *(const uint4*)(p + 8);
        *(uint4*)(buf + 16) = *(const uint4*)(p + 16);
        *(uint4*)(buf + 24) = *(const uint4*)(p + 24);
#pragma unroll
        for (int j = 0; j < 16; j++) {
            float a = bf2f(buf[j]), b = bf2f(buf[j + 16]);
            float c = tp[j].x, sn = tp[j].y;
            outb[2 * j]     = f2bf(a * c - b * sn);
            outb[2 * j + 1] = f2bf(a * sn + b * c);
        }
        *(uint4*)(p)      = *(uint4*)(outb);
        *(uint4*)(p + 8)  = *(uint4*)(outb + 8);
        *(uint4*)(p + 16) = *(uint4*)(outb + 16);
        *(uint4*)(p + 24) = *(uint4*)(outb + 24);
    }
}

// ---------------------------------------------------------------------------
// C[M,N] = A[M,K](bf16) * BT[N,K]^T(bf16) + bias[N].  m97 structure:
// 128x128 tile, BK=32, 256 threads (4 waves, 2x2 of 64x64, 4x4 MFMA frags),
// global_load_lds width-16 staging of both operands into linear LDS.
// As/Bs: [row][k], stride 32 u16 (no pad -- gload_lds needs linear dest).
// ---------------------------------------------------------------------------
template<int OUT_F32>
__global__ __launch_bounds__(256) void gemm_bt_kernel(
    const u16* __restrict__ A, const u16* __restrict__ BT,
    const float* __restrict__ bias, void* __restrict__ Cv,
    int M, int N, int K) {
    constexpr int BK = 32;
    __shared__ u16 As[128 * BK];
    __shared__ u16 Bs[128 * BK];

    const int tid  = threadIdx.x;
    const int lane = tid & 63;
    const int wave = tid >> 6;
    const int quad = lane >> 4;
    const int lm   = lane & 15;
    const int m0 = blockIdx.y * 128;
    const int n0 = blockIdx.x * 128;
    const int wm = (wave >> 1) * 64;
    const int wn = (wave & 1) * 64;

    const f32x4 fz = {0.f, 0.f, 0.f, 0.f};
    f32x4 acc[4][4];
#pragma unroll
    for (int i = 0; i < 4; i++)
#pragma unroll
        for (int j = 0; j < 4; j++) acc[i][j] = fz;

    // Staging map: 8KB per operand per k-step = 512 chunks of 16B.
    // chunk g -> row = g>>2, kpart = g&3; dest u16 offset = g*8 (linear).
    // call i in {0,1}: g = i*256 + wave*64 + lane.
    const int g0 = wave * 64 + lane;
    const int g1 = g0 + 256;
    const u16* aS0 = A  + (size_t)(m0 + (g0 >> 2)) * K + (g0 & 3) * 8;
    const u16* aS1 = A  + (size_t)(m0 + (g1 >> 2)) * K + (g1 & 3) * 8;
    const u16* bS0 = BT + (size_t)(n0 + (g0 >> 2)) * K + (g0 & 3) * 8;
    const u16* bS1 = BT + (size_t)(n0 + (g1 >> 2)) * K + (g1 & 3) * 8;
    u16* aD0 = As + (size_t)wave * 512;
    u16* aD1 = aD0 + 2048;
    u16* bD0 = Bs + (size_t)wave * 512;
    u16* bD1 = bD0 + 2048;

    for (int k0 = 0; k0 < K; k0 += BK) {
        GLD16(aS0 + k0, aD0);
        GLD16(aS1 + k0, aD1);
        GLD16(bS0 + k0, bD0);
        GLD16(bS1 + k0, bD1);
        __syncthreads();   // compiler drains vmcnt before barrier

        bf16x8 a[4], b[4];
#pragma unroll
        for (int i = 0; i < 4; i++)
            a[i] = *(const bf16x8*)(As + (wm + i * 16 + lm) * BK + quad * 8);
#pragma unroll
        for (int i = 0; i < 4; i++)
            b[i] = *(const bf16x8*)(Bs + (wn + i * 16 + lm) * BK + quad * 8);
#pragma unroll
        for (int i = 0; i < 4; i++)
#pragma unroll
            for (int j = 0; j < 4; j++)
                acc[i][j] = MFMA16(a[i], b[j], acc[i][j]);
        __syncthreads();
    }

    // epilogue: C/D layout col=lane&15, row=quad*4+reg
#pragma unroll
    for (int j = 0; j < 4; j++) {
        int col = n0 + wn + j * 16 + lm;
        float bv = bias[col];
#pragma unroll
        for (int i = 0; i < 4; i++) {
            int rowb = m0 + wm + i * 16 + quad * 4;
#pragma unroll
            for (int r = 0; r < 4; r++) {
                float v = acc[i][j][r] + bv;
                if (OUT_F32) ((float*)Cv)[(size_t)(rowb + r) * N + col] = v;
                else         ((u16*)Cv)[(size_t)(rowb + r) * N + col] = f2bf(v);
            }
        }
    }
}

// ---------------------------------------------------------------------------
// Flash attention, exact online softmax. q/k/v bf16 (ws), Bias fp32, O bf16.
// Block = (q_tile of 64 rows, h, b); 4 waves x 16 q-rows each.
// ---------------------------------------------------------------------------
__global__ __launch_bounds__(256) void attn_kernel(
    const u16* __restrict__ Q, const u16* __restrict__ Kv,
    const u16* __restrict__ V, const float* __restrict__ Bias,
    u16* __restrict__ O) {
    constexpr int S = 1024, H = 32, HD = 128;
    constexpr int KST = 136;   // 272B rows: 16B aligned, banks spread
    constexpr int VST = 40;    // 80B rows
    __shared__ u16 Ks[32 * KST];
    __shared__ u16 Vst[128 * VST];
    __shared__ u16 Ps[4 * 16 * VST];

    const int tid  = threadIdx.x;
    const int lane = tid & 63;
    const int wave = tid >> 6;
    const int quad = lane >> 4;
    const int lm   = lane & 15;
    const int qt = blockIdx.x;
    const int h  = blockIdx.y;
    const int b  = blockIdx.z;
    const int qrow = qt * 64 + wave * 16;

    const u16* qb = Q + (((size_t)b * S + qrow + lm) * H + h) * HD;
    bf16x8 qf[4];
#pragma unroll
    for (int f = 0; f < 4; f++)
        qf[f] = *(const bf16x8*)(qb + f * 32 + quad * 8);

    float m_run[4], l_run[4], alpha[4];
#pragma unroll
    for (int r = 0; r < 4; r++) { m_run[r] = -3.0e38f; l_run[r] = 0.f; }
    const f32x4 fz = {0.f, 0.f, 0.f, 0.f};
    f32x4 oacc[8];
#pragma unroll
    for (int t = 0; t < 8; t++) oacc[t] = fz;

    const float scale = 0.08838834764831845f;  // 1/sqrt(128)

    for (int kt = 0; kt < S / 32; kt++) {
        const int key0 = kt * 32;
#pragma unroll
        for (int i = 0; i < 2; i++) {
            int c = tid + i * 256;
            int row = c >> 4, part = c & 15;
            const uint4* src = (const uint4*)(Kv + (((size_t)b * S + key0 + row) * H + h) * HD + part * 8);
            *(uint4*)(Ks + row * KST + part * 8) = *src;
        }
#pragma unroll
        for (int i = 0; i < 2; i++) {
            int w = tid + i * 256;
            int hd = w & 127, kc = w >> 7;
            const u16* src = V + (((size_t)b * S + key0 + kc * 8) * H + h) * HD + hd;
            union { u16 u[8]; uint4 v; } t;
#pragma unroll
            for (int j = 0; j < 8; j++) t.u[j] = src[(size_t)j * H * HD];
            *(uint4*)(Vst + hd * VST + kc * 8) = t.v;
        }
        __syncthreads();

        f32x4 sc[2];
#pragma unroll
        for (int kt2 = 0; kt2 < 2; kt2++) {
            f32x4 c = fz;
#pragma unroll
            for (int f = 0; f < 4; f++) {
                bf16x8 kf = *(const bf16x8*)(Ks + (kt2 * 16 + lm) * KST + f * 32 + quad * 8);
                c = MFMA16(qf[f], kf, c);
            }
            sc[kt2] = c;
        }

#pragma unroll
        for (int r = 0; r < 4; r++) {
            int qr = qrow + quad * 4 + r;
            float s0 = sc[0][r] * scale + Bias[(size_t)qr * S + key0 + lm];
            float s1 = sc[1][r] * scale + Bias[(size_t)qr * S + key0 + 16 + lm];
            float mx = fmaxf(s0, s1);
#pragma unroll
            for (int d = 1; d < 16; d <<= 1) mx = fmaxf(mx, __shfl_xor(mx, d));
            float mnew = fmaxf(m_run[r], mx);
            alpha[r] = __expf(m_run[r] - mnew);
            float p0 = __expf(s0 - mnew);
            float p1 = __expf(s1 - mnew);
            float ps = p0 + p1;
#pragma unroll
            for (int d = 1; d < 16; d <<= 1) ps += __shfl_xor(ps, d);
            l_run[r] = l_run[r] * alpha[r] + ps;
            m_run[r] = mnew;
            Ps[wave * (16 * VST) + (quad * 4 + r) * VST + lm]      = f2bf(p0);
            Ps[wave * (16 * VST) + (quad * 4 + r) * VST + 16 + lm] = f2bf(p1);
        }
#pragma unroll
        for (int t = 0; t < 8; t++)
#pragma unroll
            for (int r = 0; r < 4; r++) oacc[t][r] *= alpha[r];
        __syncthreads();

        bf16x8 pf = *(const bf16x8*)(Ps + wave * (16 * VST) + lm * VST + quad * 8);
#pragma unroll
        for (int t = 0; t < 8; t++) {
            bf16x8 vf = *(const bf16x8*)(Vst + (t * 16 + lm) * VST + quad * 8);
            oacc[t] = MFMA16(pf, vf, oacc[t]);
        }
        __syncthreads();
    }

    u16* ob = O + (((size_t)b * S + qrow) * H + h) * HD;
#pragma unroll
    for (int r = 0; r < 4; r++) {
        float inv = 1.0f / l_run[r];
#pragma unroll
        for (int t = 0; t < 8; t++) {
            int hd = t * 16 + lm;
            ob[(size_t)(quad * 4 + r) * H * HD + hd] = f2bf(oacc[t][r] * inv);
        }
    }
}

// ---------------------------------------------------------------------------
extern "C" void kernel_launch(void* const* d_in, const int* in_sizes, int n_in,
                              void* d_out, int out_size, void* d_ws, size_t ws_size,
                              hipStream_t stream) {
    const float* x   = (const float*)d_in[0];
    const float* ab  = (const float*)d_in[1];
    const float* wq  = (const float*)d_in[2];
    const float* wqb = (const float*)d_in[3];
    const float* wk  = (const float*)d_in[4];
    const float* wkb = (const float*)d_in[5];
    const float* wv  = (const float*)d_in[6];
    const float* wvb = (const float*)d_in[7];
    const float* wo  = (const float*)d_in[8];
    const float* wob = (const float*)d_in[9];
    float* out = (float*)d_out;

    const size_t MAT = (size_t)4096 * 4096;
    u16* qb = (u16*)d_ws;
    u16* kb = qb + MAT;
    u16* vb = kb + MAT;
    u16* ob = vb + MAT;
    u16* xb = ob + MAT;            // x as bf16 (reused by 3 GEMMs)
    u16* wt = xb + MAT;            // shared W^T bf16 slot (reused 4x)
    float2* tab = (float2*)(wt + MAT);

    rope_table_kernel<<<64, 256, 0, stream>>>(tab);
    xcast_kernel<<<8192, 256, 0, stream>>>(x, xb, (int)MAT);

    dim3 g(32, 32);
    dim3 wtg(64, 64);
    wt_kernel<<<wtg, 256, 0, stream>>>(wq, wt, 4096, 4096);
    gemm_bt_kernel<0><<<g, 256, 0, stream>>>(xb, wt, wqb, qb, 4096, 4096, 4096);
    wt_kernel<<<wtg, 256, 0, stream>>>(wk, wt, 4096, 4096);
    gemm_bt_kernel<0><<<g, 256, 0, stream>>>(xb, wt, wkb, kb, 4096, 4096, 4096);
    wt_kernel<<<wtg, 256, 0, stream>>>(wv, wt, 4096, 4096);
    gemm_bt_kernel<0><<<g, 256, 0, stream>>>(xb, wt, wvb, vb, 4096, 4096, 4096);

    rope_apply_kernel<<<512, 256, 0, stream>>>(qb, kb, tab);
    attn_kernel<<<dim3(16, 32, 4), 256, 0, stream>>>(qb, kb, vb, ab, ob);

    wt_kernel<<<wtg, 256, 0, stream>>>(wo, wt, 4096, 4096);
    gemm_bt_kernel<1><<<g, 256, 0, stream>>>(ob, wt, wob, out, 4096, 4096, 4096);
}